// Round 1
// baseline (416.622 us; speedup 1.0000x reference)
//
#include <hip/hip_runtime.h>
#include <stdint.h>

// ---------------- constants ----------------
constexpr int IMG     = 3072;
constexpr int NPIX    = IMG * IMG;        // 9437184
constexpr int PH      = 384;              // patch height/width
constexpr int NPATCH  = 64;
constexpr int NB1     = 8192;             // level-1 bins over [0.5,1): (key-0x3F000000)>>10
constexpr int NB2     = 1024;             // level-2: low 10 mantissa bits (1 ulp each)
constexpr int WPR     = IMG / 32;         // 96 words per row
constexpr int NWORDS  = NPIX / 32;        // 294912
constexpr uint32_t KEY_LO = 0x3F000000u;  // bits(0.5f)
constexpr uint32_t KEY_HI = 0x3F800000u;  // bits(1.0f)
// Exact fp32 bit-step of +-5e-5f for th in [0.5,1):
//   5e-5f = 13743895 * 2^-38;  13743895 = 838*16384 + 14103
//   add: frac 14103/16384 > 1/2 -> +839 ulps ; sub: frac 2281/16384 < 1/2 -> -839 ulps
constexpr int STEP_ULPS = 839;

// ---------------- workspace layout (bytes) ----------------
constexpr size_t OFF_HIST1   = 0;
constexpr size_t OFF_ABOVE   = OFF_HIST1 + (size_t)NPATCH * NB1 * 4;       // 2097152
constexpr size_t OFF_HIST2   = OFF_ABOVE + 256;                            // 2097408
constexpr size_t OFF_SELBIN  = OFF_HIST2 + (size_t)NPATCH * 2 * NB2 * 4;   // 2621696
constexpr size_t OFF_SELRANK = OFF_SELBIN + 512;
constexpr size_t OFF_THS     = OFF_SELRANK + 512;
constexpr size_t OFF_B       = OFF_THS + 256;
constexpr size_t OFF_HB      = OFF_B  + (size_t)NWORDS * 4;
constexpr size_t OFF_DB      = OFF_HB + (size_t)NWORDS * 4;
constexpr size_t ZERO_BYTES  = OFF_SELBIN;   // hist1 + above + hist2 must be zeroed

__device__ __forceinline__ bool is_frame(int p) {
    int pr = p >> 3, pc = p & 7;
    return pr == 0 || pr == 7 || pc == 0 || pc == 7;
}

// Integer count boundaries reproducing fp32 mean/compare semantics:
//   K_lo = min c : fl(c/147456) >= lo  ;  C_hi = max c : fl(c/147456) <= hi
__device__ void compute_ranks(bool frame, int& R1, int& R2) {
    float fb = frame ? 0.05f : 0.0f;
    float lo = 0.12f - fb;   // == fl32(PATCH_MEAN+0.02) - fb, fp32 arithmetic
    float hi = 0.08f - fb;
    int c = (int)((double)lo * 147456.0);
    while (c > 0 && (float)(c - 1) / 147456.0f >= lo) --c;
    while ((float)c / 147456.0f < lo) ++c;
    int d = (int)((double)hi * 147456.0);
    while ((float)(d + 1) / 147456.0f <= hi) ++d;
    while (d > 0 && (float)d / 147456.0f > hi) --d;
    R1 = c - 1;   // 0-indexed descending rank of v1 (K_lo-th largest)
    R2 = d;       // 0-indexed descending rank of v2 ((C_hi+1)-th largest)
}

// ---------------- pass 1: level-1 histogram ----------------
__global__ __launch_bounds__(256) void k_hist1(const float* __restrict__ x,
                                               uint32_t* __restrict__ hist1,
                                               uint32_t* __restrict__ above) {
    int t = blockIdx.x * blockDim.x + threadIdx.x;
    int base = t * 4;
    if (base >= NPIX) return;
    int y = base / IMG;
    int col = base - y * IMG;
    int patch = (y / PH) * 8 + (col / PH);
    float4 v = *reinterpret_cast<const float4*>(x + base);
    float vals[4] = {v.x, v.y, v.z, v.w};
    uint32_t* hp = hist1 + (size_t)patch * NB1;
#pragma unroll
    for (int k = 0; k < 4; ++k) {
        uint32_t key = __float_as_uint(vals[k]);
        if (key >= KEY_LO) {
            if (key < KEY_HI) atomicAdd(hp + ((key - KEY_LO) >> 10), 1u);
            else              atomicAdd(above + patch, 1u);
        }
    }
}

// ---------------- pass 2: locate bin per (patch, rank) ----------------
__global__ __launch_bounds__(256) void k_findbin(const uint32_t* __restrict__ hist1,
                                                 const uint32_t* __restrict__ above,
                                                 uint32_t* __restrict__ sel_bin,
                                                 uint32_t* __restrict__ sel_rank) {
    __shared__ uint32_t partial[256];
    __shared__ uint32_t scan[257];
    int p = blockIdx.x;
    int t = threadIdx.x;
    const uint32_t* hp = hist1 + (size_t)p * NB1;
    // thread t sums 32 bins descending from the top
    int topbin = NB1 - 1 - 32 * t;
    uint32_t s = 0;
    for (int i = 0; i < 32; ++i) s += hp[topbin - i];
    partial[t] = s;
    __syncthreads();
    if (t == 0) {
        uint32_t acc = above[p];
        for (int i = 0; i < 256; ++i) { scan[i] = acc; acc += partial[i]; }
        scan[256] = acc;
        int R[2];
        compute_ranks(is_frame(p), R[0], R[1]);
        for (int j = 0; j < 2; ++j) {
            int rank = R[j];
            if (rank < (int)scan[0])       rank = (int)scan[0];        // safety (v>=1.0)
            if (rank >= (int)scan[256])    rank = (int)scan[256] - 1;  // safety (v<0.5)
            int seg = 255;
            for (int i = 0; i < 256; ++i)
                if (rank < (int)scan[i + 1]) { seg = i; break; }
            uint32_t cum = scan[seg];
            int tb = NB1 - 1 - 32 * seg;
            int bin = tb - 31; uint32_t r = 0;
            for (int i = 0; i < 32; ++i) {
                uint32_t h = hp[tb - i];
                if ((uint32_t)rank < cum + h) { bin = tb - i; r = (uint32_t)rank - cum; break; }
                cum += h;
            }
            sel_bin[p * 2 + j]  = (uint32_t)bin;
            sel_rank[p * 2 + j] = r;
        }
    }
}

// ---------------- pass 3: 1-ulp sub-histogram of the selected bins ----------------
__global__ __launch_bounds__(256) void k_hist2(const float* __restrict__ x,
                                               const uint32_t* __restrict__ sel_bin,
                                               uint32_t* __restrict__ hist2) {
    int t = blockIdx.x * blockDim.x + threadIdx.x;
    int base = t * 4;
    if (base >= NPIX) return;
    int y = base / IMG;
    int col = base - y * IMG;
    int patch = (y / PH) * 8 + (col / PH);
    uint32_t b0 = sel_bin[patch * 2 + 0];
    uint32_t b1 = sel_bin[patch * 2 + 1];
    float4 v = *reinterpret_cast<const float4*>(x + base);
    float vals[4] = {v.x, v.y, v.z, v.w};
#pragma unroll
    for (int k = 0; k < 4; ++k) {
        uint32_t key = __float_as_uint(vals[k]);
        if (key >= KEY_LO && key < KEY_HI) {
            uint32_t bin = (key - KEY_LO) >> 10;
            uint32_t sub = key & 1023u;
            if (bin == b0) atomicAdd(hist2 + (size_t)(patch * 2 + 0) * NB2 + sub, 1u);
            if (bin == b1) atomicAdd(hist2 + (size_t)(patch * 2 + 1) * NB2 + sub, 1u);
        }
    }
}

// ---------------- pass 4: exact order stats + sequential th chain ----------------
__global__ __launch_bounds__(128) void k_thresh(const uint32_t* __restrict__ hist2,
                                                const uint32_t* __restrict__ sel_bin,
                                                const uint32_t* __restrict__ sel_rank,
                                                float* __restrict__ ths) {
    __shared__ uint32_t vbits[NPATCH * 2];
    int t = threadIdx.x;  // 128 threads: (patch, j)
    {
        const uint32_t* h = hist2 + (size_t)t * NB2;
        uint32_t r = sel_rank[t];
        uint32_t cum = 0, sub = 0;
        for (int s2 = NB2 - 1; s2 >= 0; --s2) {
            uint32_t c2 = cum + h[s2];
            if (r < c2) { sub = (uint32_t)s2; break; }
            cum = c2;
        }
        vbits[t] = KEY_LO + (sel_bin[t] << 10) + sub;
    }
    __syncthreads();
    if (t == 0) {
        // Replicate: th carried across patches; loops move th by exactly +-839 ulps/step.
        uint32_t b = __float_as_uint(0.85f);  // 0x3F59999A
        for (int p = 0; p < NPATCH; ++p) {
            uint32_t bv1 = vbits[2 * p], bv2 = vbits[2 * p + 1];
            // loop1: while count < K_lo (v1 <= th): th -= S.  Exit first b' < bv1.
            int d1 = (int)b - (int)bv1;
            if (d1 >= 0) b -= (uint32_t)(STEP_ULPS * (d1 / STEP_ULPS + 1));
            // loop2: while count > C_hi (v2 > th): th += S.  Exit first b' >= bv2.
            int d2 = (int)bv2 - (int)b;
            if (d2 > 0) b += (uint32_t)(STEP_ULPS * ((d2 + STEP_ULPS - 1) / STEP_ULPS));
            ths[p] = __uint_as_float(b);
        }
    }
}

// ---------------- pass 5: binarize + bit-pack ----------------
__global__ __launch_bounds__(256) void k_pack(const float* __restrict__ x,
                                              const float* __restrict__ ths,
                                              uint32_t* __restrict__ B) {
    int wi = blockIdx.x * blockDim.x + threadIdx.x;
    if (wi >= NWORDS) return;
    int y  = wi / WPR;
    int wx = wi - y * WPR;
    int x0 = wx * 32;
    float th = ths[(y / PH) * 8 + (x0 / PH)];
    const float* row = x + (size_t)y * IMG + x0;
    uint32_t m = 0;
#pragma unroll
    for (int k = 0; k < 8; ++k) {
        float4 v = *reinterpret_cast<const float4*>(row + 4 * k);
        m |= (uint32_t)(v.x > th) << (4 * k + 0);
        m |= (uint32_t)(v.y > th) << (4 * k + 1);
        m |= (uint32_t)(v.z > th) << (4 * k + 2);
        m |= (uint32_t)(v.w > th) << (4 * k + 3);
    }
    B[wi] = m;
}

// ---------------- morphology: 5x5 close, bit-packed, separable ----------------
__device__ __forceinline__ uint32_t hshift5_or(uint32_t c, uint32_t l, uint32_t r) {
    uint64_t xr = ((uint64_t)r << 32) | c;
    uint64_t xl = ((uint64_t)c << 32) | l;
    return c | (uint32_t)(xr >> 1) | (uint32_t)(xr >> 2)
             | (uint32_t)(xl >> 31) | (uint32_t)(xl >> 30);
}
__device__ __forceinline__ uint32_t hshift5_and(uint32_t c, uint32_t l, uint32_t r) {
    uint64_t xr = ((uint64_t)r << 32) | c;
    uint64_t xl = ((uint64_t)c << 32) | l;
    return c & (uint32_t)(xr >> 1) & (uint32_t)(xr >> 2)
             & (uint32_t)(xl >> 31) & (uint32_t)(xl >> 30);
}

__global__ __launch_bounds__(256) void k_hdil(const uint32_t* __restrict__ B,
                                              uint32_t* __restrict__ O) {
    int wi = blockIdx.x * blockDim.x + threadIdx.x;
    if (wi >= NWORDS) return;
    int y = wi / WPR, wx = wi - y * WPR;
    uint32_t c = B[wi];
    uint32_t l = (wx > 0)       ? B[wi - 1] : 0u;
    uint32_t r = (wx < WPR - 1) ? B[wi + 1] : 0u;
    O[wi] = hshift5_or(c, l, r);
}
__global__ __launch_bounds__(256) void k_vdil(const uint32_t* __restrict__ B,
                                              uint32_t* __restrict__ O) {
    int wi = blockIdx.x * blockDim.x + threadIdx.x;
    if (wi >= NWORDS) return;
    int y = wi / WPR;
    uint32_t res = B[wi];
    if (y >= 1)       res |= B[wi - WPR];
    if (y >= 2)       res |= B[wi - 2 * WPR];
    if (y <= IMG - 2) res |= B[wi + WPR];
    if (y <= IMG - 3) res |= B[wi + 2 * WPR];
    O[wi] = res;
}
__global__ __launch_bounds__(256) void k_herode(const uint32_t* __restrict__ B,
                                                uint32_t* __restrict__ O) {
    int wi = blockIdx.x * blockDim.x + threadIdx.x;
    if (wi >= NWORDS) return;
    int y = wi / WPR, wx = wi - y * WPR;
    uint32_t c = B[wi];
    uint32_t l = (wx > 0)       ? B[wi - 1] : 0xFFFFFFFFu;
    uint32_t r = (wx < WPR - 1) ? B[wi + 1] : 0xFFFFFFFFu;
    O[wi] = hshift5_and(c, l, r);
}
__global__ __launch_bounds__(256) void k_verode_store(const uint32_t* __restrict__ B,
                                                      float* __restrict__ out) {
    int wi = blockIdx.x * blockDim.x + threadIdx.x;
    if (wi >= NWORDS) return;
    int y = wi / WPR, wx = wi - y * WPR;
    uint32_t res = B[wi];
    if (y >= 1)       res &= B[wi - WPR];
    if (y >= 2)       res &= B[wi - 2 * WPR];
    if (y <= IMG - 2) res &= B[wi + WPR];
    if (y <= IMG - 3) res &= B[wi + 2 * WPR];
    float* o = out + (size_t)y * IMG + wx * 32;
#pragma unroll
    for (int k = 0; k < 8; ++k) {
        float4 v;
        v.x = (res & (1u << (4 * k + 0))) ? 1.0f : 0.0f;
        v.y = (res & (1u << (4 * k + 1))) ? 1.0f : 0.0f;
        v.z = (res & (1u << (4 * k + 2))) ? 1.0f : 0.0f;
        v.w = (res & (1u << (4 * k + 3))) ? 1.0f : 0.0f;
        *reinterpret_cast<float4*>(o + 4 * k) = v;
    }
}

extern "C" void kernel_launch(void* const* d_in, const int* in_sizes, int n_in,
                              void* d_out, int out_size, void* d_ws, size_t ws_size,
                              hipStream_t stream) {
    const float* x = (const float*)d_in[0];
    float* out = (float*)d_out;
    uint8_t* ws = (uint8_t*)d_ws;

    uint32_t* hist1    = (uint32_t*)(ws + OFF_HIST1);
    uint32_t* above    = (uint32_t*)(ws + OFF_ABOVE);
    uint32_t* hist2    = (uint32_t*)(ws + OFF_HIST2);
    uint32_t* sel_bin  = (uint32_t*)(ws + OFF_SELBIN);
    uint32_t* sel_rank = (uint32_t*)(ws + OFF_SELRANK);
    float*    ths      = (float*)(ws + OFF_THS);
    uint32_t* Bb       = (uint32_t*)(ws + OFF_B);
    uint32_t* Hb       = (uint32_t*)(ws + OFF_HB);
    uint32_t* Db       = (uint32_t*)(ws + OFF_DB);

    hipMemsetAsync(ws, 0, ZERO_BYTES, stream);

    int g4 = (NPIX / 4 + 255) / 256;        // 9216
    int gw = (NWORDS + 255) / 256;          // 1152

    k_hist1<<<g4, 256, 0, stream>>>(x, hist1, above);
    k_findbin<<<NPATCH, 256, 0, stream>>>(hist1, above, sel_bin, sel_rank);
    k_hist2<<<g4, 256, 0, stream>>>(x, sel_bin, hist2);
    k_thresh<<<1, 128, 0, stream>>>(hist2, sel_bin, sel_rank, ths);
    k_pack<<<gw, 256, 0, stream>>>(x, ths, Bb);
    k_hdil<<<gw, 256, 0, stream>>>(Bb, Hb);
    k_vdil<<<gw, 256, 0, stream>>>(Hb, Db);
    k_herode<<<gw, 256, 0, stream>>>(Db, Hb);
    k_verode_store<<<gw, 256, 0, stream>>>(Hb, out);
}

// Round 3
// 167.235 us; speedup vs baseline: 2.4912x; 2.4912x over previous
//
#include <hip/hip_runtime.h>
#include <stdint.h>

// ---------------- constants ----------------
constexpr int IMG     = 3072;
constexpr int NPIX    = IMG * IMG;        // 9437184
constexpr int PH      = 384;              // patch height/width
constexpr int NPATCH  = 64;
constexpr int NB1     = 8192;             // level-1 bins over [0.5,1): (key-0x3F000000)>>10
constexpr int NB2     = 1024;             // level-2: low 10 mantissa bits (1 ulp each)
constexpr int WPR     = IMG / 32;         // 96 words per row
constexpr int NWORDS  = NPIX / 32;        // 294912 = 1152*256 exactly
constexpr uint32_t KEY_LO = 0x3F000000u;  // bits(0.5f)
constexpr uint32_t KEY_HI = 0x3F800000u;  // bits(1.0f)
// Exact fp32 bit-step of +-5e-5f for th in [0.5,1): +-839 ulps per step (no RNE ties)
constexpr int STEP_ULPS = 839;

// ---------------- workspace layout (bytes) ----------------
constexpr size_t OFF_VB = 0;                              // vbits: 128 u32
constexpr size_t OFF_B  = 512;                            // packed binary
constexpr size_t OFF_D  = OFF_B + (size_t)NWORDS * 4;     // dilated

__device__ __forceinline__ bool is_frame(int p) {
    int pr = p >> 3, pc = p & 7;
    return pr == 0 || pr == 7 || pc == 0 || pc == 7;
}

// Integer count boundaries reproducing fp32 mean/compare semantics (verified R1):
//   K_lo = min c : fl(c/147456) >= lo  ;  C_hi = max c : fl(c/147456) <= hi
__device__ void compute_ranks(bool frame, int& R1, int& R2) {
    float fb = frame ? 0.05f : 0.0f;
    float lo = 0.12f - fb;
    float hi = 0.08f - fb;
    int c = (int)((double)lo * 147456.0);
    while (c > 0 && (float)(c - 1) / 147456.0f >= lo) --c;
    while ((float)c / 147456.0f < lo) ++c;
    int d = (int)((double)hi * 147456.0);
    while ((float)(d + 1) / 147456.0f <= hi) ++d;
    while (d > 0 && (float)d / 147456.0f > hi) --d;
    R1 = c - 1;   // 0-indexed descending rank of v1 (K_lo-th largest)
    R2 = d;       // 0-indexed descending rank of v2 ((C_hi+1)-th largest)
}

// ---------------- pass 1: per-patch exact order stats, all in LDS ----------------
// One block per patch. Phase A: 8192-bin LDS histogram. Phase B: descending-rank
// bin search. Phase C: 1-ulp sub-histograms of the two selected bins (re-reads the
// L2-hot patch). Phase D: exact value bits for both ranks -> vbits[p*2+j].
__global__ __launch_bounds__(1024) void k_patch_stats(const float* __restrict__ x,
                                                      uint32_t* __restrict__ vbits_out) {
    __shared__ uint32_t hist[NB1];          // 32 KB
    __shared__ uint32_t partials[1024];     // desc sums of 8 bins each
    __shared__ uint32_t partial2[64];       // desc sums of 16 partials each
    __shared__ uint32_t sub[2][NB2];        // 8 KB
    __shared__ uint32_t spart[128];         // sub partials: 16 sub-bins each
    __shared__ uint32_t above_s;
    __shared__ uint32_t sel_bin_s[2];
    __shared__ uint32_t sel_rank_s[2];

    const int p = blockIdx.x;
    const int t = threadIdx.x;
    const int pr = p >> 3, pc = p & 7;
    const float* pbase = x + (size_t)(pr * PH) * IMG + pc * PH;

    for (int i = t; i < NB1; i += 1024) hist[i] = 0;
    if (t == 0) above_s = 0;
    __syncthreads();

    // Phase A: level-1 histogram. Patch = 384 rows x 96 float4.
    constexpr int NF4 = PH * PH / 4;  // 36864
    for (int i = t; i < NF4; i += 1024) {
        int r = i / 96;
        int c = i - r * 96;
        float4 v = *reinterpret_cast<const float4*>(pbase + (size_t)r * IMG + c * 4);
        float vals[4] = {v.x, v.y, v.z, v.w};
#pragma unroll
        for (int k = 0; k < 4; ++k) {
            uint32_t key = __float_as_uint(vals[k]);
            if (key >= KEY_LO) {
                if (key < KEY_HI) atomicAdd(&hist[(key - KEY_LO) >> 10], 1u);
                else              atomicAdd(&above_s, 1u);
            }
        }
    }
    __syncthreads();

    // Phase B: locate the two (bin, within-bin rank) pairs. Descending order:
    // d-th largest bin is index NB1-1-d; "above" values precede all bins.
    {
        uint32_t s = 0;
#pragma unroll
        for (int b = 0; b < 8; ++b) s += hist[NB1 - 1 - (8 * t + b)];
        partials[t] = s;
    }
    __syncthreads();
    if (t < 64) {
        uint32_t s = 0;
#pragma unroll
        for (int k = 0; k < 16; ++k) s += partials[16 * t + k];
        partial2[t] = s;
    }
    __syncthreads();
    if (t == 0) {
        uint32_t above = above_s;
        uint32_t total = above;
        for (int u = 0; u < 64; ++u) total += partial2[u];
        int R[2];
        compute_ranks(is_frame(p), R[0], R[1]);
        for (int j = 0; j < 2; ++j) {
            int rank = R[j];
            if (rank < (int)above)  rank = (int)above;       // safety: v >= 1.0
            if (rank >= (int)total) rank = (int)total - 1;   // safety: v < 0.5
            uint32_t cum = above;
            int u = 63;
            for (int i = 0; i < 64; ++i) {
                if ((uint32_t)rank < cum + partial2[i]) { u = i; break; }
                cum += partial2[i];
            }
            int k = 15;
            for (int i = 0; i < 16; ++i) {
                if ((uint32_t)rank < cum + partials[16 * u + i]) { k = i; break; }
                cum += partials[16 * u + i];
            }
            int base_d = 8 * (16 * u + k);
            uint32_t bin = NB1 - 1 - base_d, r = 0;
            for (int b = 0; b < 8; ++b) {
                uint32_t h = hist[NB1 - 1 - (base_d + b)];
                if ((uint32_t)rank < cum + h) { bin = NB1 - 1 - (base_d + b); r = (uint32_t)rank - cum; break; }
                cum += h;
            }
            sel_bin_s[j] = bin;
            sel_rank_s[j] = r;
        }
    }
    // Phase C: zero BOTH sub-hists (R2 bug: blockDim==NB2 meant sub[1] was never
    // zeroed), then re-read patch, 1-ulp sub-histogram of the two selected bins.
    if (t < NB2) { sub[0][t] = 0; sub[1][t] = 0; }
    __syncthreads();
    {
        uint32_t b0 = sel_bin_s[0], b1 = sel_bin_s[1];
        for (int i = t; i < NF4; i += 1024) {
            int r = i / 96;
            int c = i - r * 96;
            float4 v = *reinterpret_cast<const float4*>(pbase + (size_t)r * IMG + c * 4);
            float vals[4] = {v.x, v.y, v.z, v.w};
#pragma unroll
            for (int k = 0; k < 4; ++k) {
                uint32_t key = __float_as_uint(vals[k]);
                if (key >= KEY_LO && key < KEY_HI) {
                    uint32_t bin = (key - KEY_LO) >> 10;
                    uint32_t sb  = key & 1023u;
                    if (bin == b0) atomicAdd(&sub[0][sb], 1u);
                    if (bin == b1) atomicAdd(&sub[1][sb], 1u);
                }
            }
        }
    }
    __syncthreads();

    // Phase D: find sub-bin by descending rank, emit exact value bits
    if (t < 128) {
        int j = t >> 6, u = t & 63;
        uint32_t s = 0;
#pragma unroll
        for (int k = 0; k < 16; ++k) s += sub[j][NB2 - 1 - (16 * u + k)];
        spart[t] = s;
    }
    __syncthreads();
    if (t == 0 || t == 64) {
        int j = t >> 6;
        uint32_t rank = sel_rank_s[j];
        uint32_t cum = 0, subbin = 0;
        int u = 63;
        for (int i = 0; i < 64; ++i) {
            if (rank < cum + spart[j * 64 + i]) { u = i; break; }
            cum += spart[j * 64 + i];
        }
        for (int i = 0; i < 16; ++i) {
            int d = 16 * u + i;
            uint32_t h = sub[j][NB2 - 1 - d];
            if (rank < cum + h) { subbin = (uint32_t)(NB2 - 1 - d); break; }
            cum += h;
        }
        vbits_out[p * 2 + j] = KEY_LO + (sel_bin_s[j] << 10) + subbin;
    }
}

// ---------------- pass 2: th chain (in-block) + binarize + bit-pack ----------------
__global__ __launch_bounds__(256) void k_pack(const float* __restrict__ x,
                                              const uint32_t* __restrict__ vbits,
                                              uint32_t* __restrict__ B) {
    __shared__ uint32_t vb[128];
    __shared__ float ths_s[NPATCH];
    int t = threadIdx.x;
    if (t < 128) vb[t] = vbits[t];
    __syncthreads();
    if (t == 0) {
        // th carried across patches; loops move th by exactly +-839 ulps/step.
        uint32_t b = 0x3F59999Au;  // bits(0.85f)
        for (int p = 0; p < NPATCH; ++p) {
            uint32_t bv1 = vb[2 * p], bv2 = vb[2 * p + 1];
            int d1 = (int)b - (int)bv1;
            if (d1 >= 0) b -= (uint32_t)(STEP_ULPS * (d1 / STEP_ULPS + 1));
            int d2 = (int)bv2 - (int)b;
            if (d2 > 0) b += (uint32_t)(STEP_ULPS * ((d2 + STEP_ULPS - 1) / STEP_ULPS));
            ths_s[p] = __uint_as_float(b);
        }
    }
    __syncthreads();
    int wi = blockIdx.x * 256 + t;
    if (wi >= NWORDS) return;
    int y  = wi / WPR;
    int wx = wi - y * WPR;
    float th = ths_s[(y / PH) * 8 + (wx * 32) / PH];
    const float* row = x + (size_t)y * IMG + wx * 32;
    uint32_t m = 0;
#pragma unroll
    for (int k = 0; k < 8; ++k) {
        float4 v = *reinterpret_cast<const float4*>(row + 4 * k);
        m |= (uint32_t)(v.x > th) << (4 * k + 0);
        m |= (uint32_t)(v.y > th) << (4 * k + 1);
        m |= (uint32_t)(v.z > th) << (4 * k + 2);
        m |= (uint32_t)(v.w > th) << (4 * k + 3);
    }
    B[wi] = m;
}

// ---------------- morphology: 5x5 close, bit-packed, direct 2D ----------------
__device__ __forceinline__ uint32_t hshift5_or(uint32_t c, uint32_t l, uint32_t r) {
    uint64_t xr = ((uint64_t)r << 32) | c;
    uint64_t xl = ((uint64_t)c << 32) | l;
    return c | (uint32_t)(xr >> 1) | (uint32_t)(xr >> 2)
             | (uint32_t)(xl >> 31) | (uint32_t)(xl >> 30);
}
__device__ __forceinline__ uint32_t hshift5_and(uint32_t c, uint32_t l, uint32_t r) {
    uint64_t xr = ((uint64_t)r << 32) | c;
    uint64_t xl = ((uint64_t)c << 32) | l;
    return c & (uint32_t)(xr >> 1) & (uint32_t)(xr >> 2)
             & (uint32_t)(xl >> 31) & (uint32_t)(xl >> 30);
}

__global__ __launch_bounds__(256) void k_dil2d(const uint32_t* __restrict__ B,
                                               uint32_t* __restrict__ O) {
    int wi = blockIdx.x * 256 + threadIdx.x;
    if (wi >= NWORDS) return;
    int y = wi / WPR, wx = wi - y * WPR;
    uint32_t acc = 0;
#pragma unroll
    for (int dy = -2; dy <= 2; ++dy) {
        int yy = y + dy;
        if (yy < 0 || yy >= IMG) continue;
        int base = yy * WPR + wx;
        uint32_t c = B[base];
        uint32_t l = (wx > 0)       ? B[base - 1] : 0u;
        uint32_t r = (wx < WPR - 1) ? B[base + 1] : 0u;
        acc |= hshift5_or(c, l, r);
    }
    O[wi] = acc;
}

__global__ __launch_bounds__(256) void k_ero2d_store(const uint32_t* __restrict__ B,
                                                     float* __restrict__ out) {
    int wi = blockIdx.x * 256 + threadIdx.x;
    if (wi >= NWORDS) return;
    int y = wi / WPR, wx = wi - y * WPR;
    uint32_t acc = 0xFFFFFFFFu;
#pragma unroll
    for (int dy = -2; dy <= 2; ++dy) {
        int yy = y + dy;
        if (yy < 0 || yy >= IMG) continue;   // oob rows contribute 1s (no-op for AND)
        int base = yy * WPR + wx;
        uint32_t c = B[base];
        uint32_t l = (wx > 0)       ? B[base - 1] : 0xFFFFFFFFu;
        uint32_t r = (wx < WPR - 1) ? B[base + 1] : 0xFFFFFFFFu;
        acc &= hshift5_and(c, l, r);
    }
    float* o = out + (size_t)y * IMG + wx * 32;
#pragma unroll
    for (int k = 0; k < 8; ++k) {
        float4 v;
        v.x = (acc & (1u << (4 * k + 0))) ? 1.0f : 0.0f;
        v.y = (acc & (1u << (4 * k + 1))) ? 1.0f : 0.0f;
        v.z = (acc & (1u << (4 * k + 2))) ? 1.0f : 0.0f;
        v.w = (acc & (1u << (4 * k + 3))) ? 1.0f : 0.0f;
        *reinterpret_cast<float4*>(o + 4 * k) = v;
    }
}

extern "C" void kernel_launch(void* const* d_in, const int* in_sizes, int n_in,
                              void* d_out, int out_size, void* d_ws, size_t ws_size,
                              hipStream_t stream) {
    const float* x = (const float*)d_in[0];
    float* out = (float*)d_out;
    uint8_t* ws = (uint8_t*)d_ws;

    uint32_t* vbits = (uint32_t*)(ws + OFF_VB);
    uint32_t* Bb    = (uint32_t*)(ws + OFF_B);
    uint32_t* Db    = (uint32_t*)(ws + OFF_D);

    int gw = NWORDS / 256;  // 1152, exact

    k_patch_stats<<<NPATCH, 1024, 0, stream>>>(x, vbits);
    k_pack<<<gw, 256, 0, stream>>>(x, vbits, Bb);
    k_dil2d<<<gw, 256, 0, stream>>>(Bb, Db);
    k_ero2d_store<<<gw, 256, 0, stream>>>(Db, out);
}

// Round 4
// 166.899 us; speedup vs baseline: 2.4963x; 1.0020x over previous
//
#include <hip/hip_runtime.h>
#include <stdint.h>

// ---------------- constants ----------------
constexpr int IMG     = 3072;
constexpr int NPIX    = IMG * IMG;        // 9437184
constexpr int PH      = 384;              // patch height/width
constexpr int NPATCH  = 64;
constexpr int NSLICE  = 8;                // slices per patch (48 rows each)
constexpr int SROWS   = PH / NSLICE;      // 48
constexpr int NBC     = 1024;             // coarse bins over [0.5,1): (key-KEY_LO)>>13
constexpr int CAP     = 2048;             // per-(patch,j) candidate list capacity
constexpr int WPR     = IMG / 32;         // 96 words per row
constexpr int NWORDS  = NPIX / 32;        // 294912 = 1152*256 exactly
constexpr uint32_t KEY_LO = 0x3F000000u;  // bits(0.5f)
constexpr uint32_t KEY_HI = 0x3F800000u;  // bits(1.0f)
// Exact fp32 bit-step of +-5e-5f for th in [0.5,1): +-839 ulps per step (no RNE ties)
constexpr int STEP_ULPS = 839;

// ---------------- workspace layout (bytes) ----------------
constexpr size_t OFF_VB    = 0;                                   // 128 u32
constexpr size_t OFF_CNT   = 512;                                 // 128 u32 (memset 0)
constexpr size_t OFF_METAR = 1024;                                // 128 u32
constexpr size_t OFF_METAB = 1536;                                // 128 u32
constexpr size_t OFF_PRIV  = 2048;                                // 512*1025 u32
constexpr size_t OFF_LIST  = OFF_PRIV + (size_t)512 * 1025 * 4;   // 128*CAP u32
constexpr size_t OFF_B     = OFF_LIST + (size_t)128 * CAP * 4;
constexpr size_t OFF_D     = OFF_B + (size_t)NWORDS * 4;

__device__ __forceinline__ bool is_frame(int p) {
    int pr = p >> 3, pc = p & 7;
    return pr == 0 || pr == 7 || pc == 0 || pc == 7;
}

// Integer count boundaries reproducing fp32 mean/compare semantics (verified R1/R3):
//   K_lo = min c : fl(c/147456) >= lo  ;  C_hi = max c : fl(c/147456) <= hi
__device__ void compute_ranks(bool frame, int& R1, int& R2) {
    float fb = frame ? 0.05f : 0.0f;
    float lo = 0.12f - fb;
    float hi = 0.08f - fb;
    int c = (int)((double)lo * 147456.0);
    while (c > 0 && (float)(c - 1) / 147456.0f >= lo) --c;
    while ((float)c / 147456.0f < lo) ++c;
    int d = (int)((double)hi * 147456.0);
    while ((float)(d + 1) / 147456.0f <= hi) ++d;
    while (d > 0 && (float)d / 147456.0f > hi) --d;
    R1 = c - 1;   // 0-indexed descending rank of v1 (K_lo-th largest)
    R2 = d;       // 0-indexed descending rank of v2 ((C_hi+1)-th largest)
}

// ---------------- K1: coarse per-slice histogram (plain stores, no atomics) ----
// 512 blocks = 64 patches x 8 slices of 48 rows. 1024 bins of 8192 ulps + above.
__global__ __launch_bounds__(256) void k_coarse(const float* __restrict__ x,
                                                uint32_t* __restrict__ priv) {
    __shared__ uint32_t hist[NBC + 1];
    const int p = blockIdx.x >> 3, s = blockIdx.x & 7;
    const int t = threadIdx.x;
    const int pr = p >> 3, pc = p & 7;
    const float* base = x + (size_t)(pr * PH + s * SROWS) * IMG + pc * PH;

    for (int i = t; i < NBC + 1; i += 256) hist[i] = 0;
    __syncthreads();

    constexpr int NF4 = SROWS * (PH / 4);  // 48*96 = 4608
    for (int i = t; i < NF4; i += 256) {
        int r = i / 96, c = i - r * 96;
        float4 v = *reinterpret_cast<const float4*>(base + (size_t)r * IMG + c * 4);
        float vals[4] = {v.x, v.y, v.z, v.w};
#pragma unroll
        for (int k = 0; k < 4; ++k) {
            uint32_t key = __float_as_uint(vals[k]);
            if (key >= KEY_LO) {
                if (key < KEY_HI) atomicAdd(&hist[(key - KEY_LO) >> 13], 1u);
                else              atomicAdd(&hist[NBC], 1u);
            }
        }
    }
    __syncthreads();
    uint32_t* out = priv + (size_t)blockIdx.x * (NBC + 1);
    for (int i = t; i < NBC + 1; i += 256) out[i] = hist[i];
}

// ---------------- K2: combine + bin-locate (replicated) + candidate append ----
__global__ __launch_bounds__(256) void k_refine(const float* __restrict__ x,
                                                const uint32_t* __restrict__ priv,
                                                uint32_t* __restrict__ list,
                                                uint32_t* __restrict__ count,
                                                uint32_t* __restrict__ meta_r,
                                                uint32_t* __restrict__ meta_b) {
    __shared__ uint32_t comb[NBC + 1];
    __shared__ uint32_t partials[256];   // 4 desc bins each
    __shared__ uint32_t partial2[16];    // 16 partials each
    __shared__ uint32_t sel_bin_s[2];
    __shared__ uint32_t sel_r_s[2];
    const int p = blockIdx.x >> 3, s = blockIdx.x & 7;
    const int t = threadIdx.x;
    const int pr = p >> 3, pc = p & 7;
    const float* base = x + (size_t)(pr * PH + s * SROWS) * IMG + pc * PH;

    for (int i = t; i < NBC + 1; i += 256) {
        uint32_t sum = 0;
#pragma unroll
        for (int b = 0; b < NSLICE; ++b)
            sum += priv[(size_t)(p * NSLICE + b) * (NBC + 1) + i];
        comb[i] = sum;
    }
    __syncthreads();
    {
        uint32_t sum = 0;
#pragma unroll
        for (int k = 0; k < 4; ++k) sum += comb[NBC - 1 - (4 * t + k)];
        partials[t] = sum;
    }
    __syncthreads();
    if (t < 16) {
        uint32_t sum = 0;
#pragma unroll
        for (int k = 0; k < 16; ++k) sum += partials[16 * t + k];
        partial2[t] = sum;
    }
    __syncthreads();
    if (t == 0) {
        uint32_t above = comb[NBC];
        uint32_t total = above;
        for (int u = 0; u < 16; ++u) total += partial2[u];
        int R[2];
        compute_ranks(is_frame(p), R[0], R[1]);
        for (int j = 0; j < 2; ++j) {
            int rank = R[j];
            if (rank < (int)above)  rank = (int)above;       // safety: v >= 1.0
            if (rank >= (int)total) rank = (int)total - 1;   // safety: v < 0.5
            uint32_t cum = above;
            int u = 15;
            for (int i = 0; i < 16; ++i) {
                if ((uint32_t)rank < cum + partial2[i]) { u = i; break; }
                cum += partial2[i];
            }
            int kk = 15;
            for (int i = 0; i < 16; ++i) {
                if ((uint32_t)rank < cum + partials[16 * u + i]) { kk = i; break; }
                cum += partials[16 * u + i];
            }
            int base_d = 4 * (16 * u + kk);
            uint32_t bin = NBC - 1 - base_d, r = 0;
            for (int b = 0; b < 4; ++b) {
                uint32_t h = comb[NBC - 1 - (base_d + b)];
                if ((uint32_t)rank < cum + h) { bin = NBC - 1 - (base_d + b); r = (uint32_t)rank - cum; break; }
                cum += h;
            }
            sel_bin_s[j] = bin;
            sel_r_s[j] = r;
            if (s == 0) { meta_b[p * 2 + j] = bin; meta_r[p * 2 + j] = r; }
        }
    }
    __syncthreads();
    const uint32_t b0 = sel_bin_s[0], b1 = sel_bin_s[1];
    constexpr int NF4 = SROWS * (PH / 4);
    for (int i = t; i < NF4; i += 256) {
        int r = i / 96, c = i - r * 96;
        float4 v = *reinterpret_cast<const float4*>(base + (size_t)r * IMG + c * 4);
        float vals[4] = {v.x, v.y, v.z, v.w};
#pragma unroll
        for (int k = 0; k < 4; ++k) {
            uint32_t key = __float_as_uint(vals[k]);
            if (key >= KEY_LO && key < KEY_HI) {
                uint32_t bin = (key - KEY_LO) >> 13;
                if (bin == b0) {
                    uint32_t idx = atomicAdd(&count[p * 2 + 0], 1u);
                    if (idx < CAP) list[(size_t)(p * 2 + 0) * CAP + idx] = key;
                }
                if (bin == b1) {
                    uint32_t idx = atomicAdd(&count[p * 2 + 1], 1u);
                    if (idx < CAP) list[(size_t)(p * 2 + 1) * CAP + idx] = key;
                }
            }
        }
    }
}

// ---------------- K3: exact r-th largest from candidate list (one wave/slot) ---
__global__ __launch_bounds__(64) void k_select(const uint32_t* __restrict__ list,
                                               const uint32_t* __restrict__ count,
                                               const uint32_t* __restrict__ meta_r,
                                               const uint32_t* __restrict__ meta_b,
                                               uint32_t* __restrict__ vbits) {
    __shared__ uint32_t keys[CAP];
    __shared__ uint32_t res;
    const int slot = blockIdx.x;
    const int t = threadIdx.x;
    uint32_t n = count[slot]; if (n > CAP) n = CAP;
    uint32_t r = meta_r[slot];
    if (t == 0) res = KEY_LO + (meta_b[slot] << 13);  // fallback (empty bin: impossible here)
    for (uint32_t i = t; i < n; i += 64) keys[i] = list[(size_t)slot * CAP + i];
    __syncthreads();
    for (uint32_t ci = t; ci < n; ci += 64) {
        uint32_t c = keys[ci], gt = 0, ge = 0;
        for (uint32_t i = 0; i < n; ++i) {
            uint32_t k = keys[i];
            gt += (k > c);
            ge += (k >= c);
        }
        if (gt <= r && r < ge) res = c;  // duplicates write the same value
    }
    __syncthreads();
    if (t == 0) vbits[slot] = res;
}

// ---------------- pack: th chain (in-block) + binarize + bit-pack (R3 verified) -
__global__ __launch_bounds__(256) void k_pack(const float* __restrict__ x,
                                              const uint32_t* __restrict__ vbits,
                                              uint32_t* __restrict__ B) {
    __shared__ uint32_t vb[128];
    __shared__ float ths_s[NPATCH];
    int t = threadIdx.x;
    if (t < 128) vb[t] = vbits[t];
    __syncthreads();
    if (t == 0) {
        uint32_t b = 0x3F59999Au;  // bits(0.85f)
        for (int p = 0; p < NPATCH; ++p) {
            uint32_t bv1 = vb[2 * p], bv2 = vb[2 * p + 1];
            int d1 = (int)b - (int)bv1;
            if (d1 >= 0) b -= (uint32_t)(STEP_ULPS * (d1 / STEP_ULPS + 1));
            int d2 = (int)bv2 - (int)b;
            if (d2 > 0) b += (uint32_t)(STEP_ULPS * ((d2 + STEP_ULPS - 1) / STEP_ULPS));
            ths_s[p] = __uint_as_float(b);
        }
    }
    __syncthreads();
    int wi = blockIdx.x * 256 + t;
    if (wi >= NWORDS) return;
    int y  = wi / WPR;
    int wx = wi - y * WPR;
    float th = ths_s[(y / PH) * 8 + (wx * 32) / PH];
    const float* row = x + (size_t)y * IMG + wx * 32;
    uint32_t m = 0;
#pragma unroll
    for (int k = 0; k < 8; ++k) {
        float4 v = *reinterpret_cast<const float4*>(row + 4 * k);
        m |= (uint32_t)(v.x > th) << (4 * k + 0);
        m |= (uint32_t)(v.y > th) << (4 * k + 1);
        m |= (uint32_t)(v.z > th) << (4 * k + 2);
        m |= (uint32_t)(v.w > th) << (4 * k + 3);
    }
    B[wi] = m;
}

// ---------------- morphology: 5x5 close, bit-packed (R3 verified) --------------
__device__ __forceinline__ uint32_t hshift5_or(uint32_t c, uint32_t l, uint32_t r) {
    uint64_t xr = ((uint64_t)r << 32) | c;
    uint64_t xl = ((uint64_t)c << 32) | l;
    return c | (uint32_t)(xr >> 1) | (uint32_t)(xr >> 2)
             | (uint32_t)(xl >> 31) | (uint32_t)(xl >> 30);
}
__device__ __forceinline__ uint32_t hshift5_and(uint32_t c, uint32_t l, uint32_t r) {
    uint64_t xr = ((uint64_t)r << 32) | c;
    uint64_t xl = ((uint64_t)c << 32) | l;
    return c & (uint32_t)(xr >> 1) & (uint32_t)(xr >> 2)
             & (uint32_t)(xl >> 31) & (uint32_t)(xl >> 30);
}

__global__ __launch_bounds__(256) void k_dil2d(const uint32_t* __restrict__ B,
                                               uint32_t* __restrict__ O) {
    int wi = blockIdx.x * 256 + threadIdx.x;
    if (wi >= NWORDS) return;
    int y = wi / WPR, wx = wi - y * WPR;
    uint32_t acc = 0;
#pragma unroll
    for (int dy = -2; dy <= 2; ++dy) {
        int yy = y + dy;
        if (yy < 0 || yy >= IMG) continue;
        int base = yy * WPR + wx;
        uint32_t c = B[base];
        uint32_t l = (wx > 0)       ? B[base - 1] : 0u;
        uint32_t r = (wx < WPR - 1) ? B[base + 1] : 0u;
        acc |= hshift5_or(c, l, r);
    }
    O[wi] = acc;
}

__global__ __launch_bounds__(256) void k_ero2d_store(const uint32_t* __restrict__ B,
                                                     float* __restrict__ out) {
    int wi = blockIdx.x * 256 + threadIdx.x;
    if (wi >= NWORDS) return;
    int y = wi / WPR, wx = wi - y * WPR;
    uint32_t acc = 0xFFFFFFFFu;
#pragma unroll
    for (int dy = -2; dy <= 2; ++dy) {
        int yy = y + dy;
        if (yy < 0 || yy >= IMG) continue;   // oob rows contribute 1s (no-op for AND)
        int base = yy * WPR + wx;
        uint32_t c = B[base];
        uint32_t l = (wx > 0)       ? B[base - 1] : 0xFFFFFFFFu;
        uint32_t r = (wx < WPR - 1) ? B[base + 1] : 0xFFFFFFFFu;
        acc &= hshift5_and(c, l, r);
    }
    float* o = out + (size_t)y * IMG + wx * 32;
#pragma unroll
    for (int k = 0; k < 8; ++k) {
        float4 v;
        v.x = (acc & (1u << (4 * k + 0))) ? 1.0f : 0.0f;
        v.y = (acc & (1u << (4 * k + 1))) ? 1.0f : 0.0f;
        v.z = (acc & (1u << (4 * k + 2))) ? 1.0f : 0.0f;
        v.w = (acc & (1u << (4 * k + 3))) ? 1.0f : 0.0f;
        *reinterpret_cast<float4*>(o + 4 * k) = v;
    }
}

extern "C" void kernel_launch(void* const* d_in, const int* in_sizes, int n_in,
                              void* d_out, int out_size, void* d_ws, size_t ws_size,
                              hipStream_t stream) {
    const float* x = (const float*)d_in[0];
    float* out = (float*)d_out;
    uint8_t* ws = (uint8_t*)d_ws;

    uint32_t* vbits  = (uint32_t*)(ws + OFF_VB);
    uint32_t* cnt    = (uint32_t*)(ws + OFF_CNT);
    uint32_t* meta_r = (uint32_t*)(ws + OFF_METAR);
    uint32_t* meta_b = (uint32_t*)(ws + OFF_METAB);
    uint32_t* priv   = (uint32_t*)(ws + OFF_PRIV);
    uint32_t* list   = (uint32_t*)(ws + OFF_LIST);
    uint32_t* Bb     = (uint32_t*)(ws + OFF_B);
    uint32_t* Db     = (uint32_t*)(ws + OFF_D);

    hipMemsetAsync(cnt, 0, 128 * 4, stream);

    int gw = NWORDS / 256;  // 1152, exact

    k_coarse<<<NPATCH * NSLICE, 256, 0, stream>>>(x, priv);
    k_refine<<<NPATCH * NSLICE, 256, 0, stream>>>(x, priv, list, cnt, meta_r, meta_b);
    k_select<<<128, 64, 0, stream>>>(list, cnt, meta_r, meta_b, vbits);
    k_pack<<<gw, 256, 0, stream>>>(x, vbits, Bb);
    k_dil2d<<<gw, 256, 0, stream>>>(Bb, Db);
    k_ero2d_store<<<gw, 256, 0, stream>>>(Db, out);
}

// Round 5
// 163.641 us; speedup vs baseline: 2.5460x; 1.0199x over previous
//
#include <hip/hip_runtime.h>
#include <stdint.h>

// ---------------- constants ----------------
constexpr int IMG     = 3072;
constexpr int NPIX    = IMG * IMG;        // 9437184
constexpr int PH      = 384;              // patch height/width
constexpr int NPATCH  = 64;
constexpr int NSLICE  = 8;                // slices per patch (48 rows each)
constexpr int SROWS   = PH / NSLICE;      // 48
constexpr int NBC     = 1024;             // coarse bins over [0.5,1): (key-KEY_LO)>>13
constexpr int CAP     = 2048;             // per-(patch,j) candidate list capacity
constexpr int WPR     = IMG / 32;         // 96 words per row
constexpr int NWORDS  = NPIX / 32;        // 294912 = 1152*256 exactly
constexpr uint32_t KEY_LO = 0x3F000000u;  // bits(0.5f)
constexpr uint32_t KEY_HI = 0x3F800000u;  // bits(1.0f)
// Exact fp32 bit-step of +-5e-5f for th in [0.5,1): +-839 ulps per step (no RNE ties)
constexpr int STEP_ULPS = 839;
// close_store tiling
constexpr int TR = 12;                    // output rows per block; 3072/12 = 256 blocks

// ---------------- workspace layout (bytes) ----------------
constexpr size_t OFF_VB    = 0;                                   // 128 u32
constexpr size_t OFF_CNT   = 512;                                 // 128 u32
constexpr size_t OFF_METAR = 1024;                                // 128 u32
constexpr size_t OFF_METAB = 1536;                                // 128 u32
constexpr size_t OFF_PRIV  = 2048;                                // 512*1025 u32
constexpr size_t OFF_LIST  = OFF_PRIV + (size_t)512 * 1025 * 4;   // 128*CAP u32
constexpr size_t OFF_B     = OFF_LIST + (size_t)128 * CAP * 4;

__device__ __forceinline__ bool is_frame(int p) {
    int pr = p >> 3, pc = p & 7;
    return pr == 0 || pr == 7 || pc == 0 || pc == 7;
}

// Integer count boundaries reproducing fp32 mean/compare semantics (verified R1/R3/R4)
__device__ void compute_ranks(bool frame, int& R1, int& R2) {
    float fb = frame ? 0.05f : 0.0f;
    float lo = 0.12f - fb;
    float hi = 0.08f - fb;
    int c = (int)((double)lo * 147456.0);
    while (c > 0 && (float)(c - 1) / 147456.0f >= lo) --c;
    while ((float)c / 147456.0f < lo) ++c;
    int d = (int)((double)hi * 147456.0);
    while ((float)(d + 1) / 147456.0f <= hi) ++d;
    while (d > 0 && (float)d / 147456.0f > hi) --d;
    R1 = c - 1;   // 0-indexed descending rank of v1 (K_lo-th largest)
    R2 = d;       // 0-indexed descending rank of v2 ((C_hi+1)-th largest)
}

// ---------------- K1: coarse per-slice histogram (plain stores, no atomics) ----
// 512 blocks = 64 patches x 8 slices of 48 rows. Block 0 also zeroes cnt[] (it is
// consumed only by k_refine, which launches after this kernel drains).
__global__ __launch_bounds__(256) void k_coarse(const float* __restrict__ x,
                                                uint32_t* __restrict__ priv,
                                                uint32_t* __restrict__ cnt) {
    __shared__ uint32_t hist[NBC + 1];
    const int p = blockIdx.x >> 3, s = blockIdx.x & 7;
    const int t = threadIdx.x;
    const int pr = p >> 3, pc = p & 7;
    const float* base = x + (size_t)(pr * PH + s * SROWS) * IMG + pc * PH;

    if (blockIdx.x == 0 && t < 128) cnt[t] = 0;
    for (int i = t; i < NBC + 1; i += 256) hist[i] = 0;
    __syncthreads();

    constexpr int NF4 = SROWS * (PH / 4);  // 48*96 = 4608
    for (int i = t; i < NF4; i += 256) {
        int r = i / 96, c = i - r * 96;
        float4 v = *reinterpret_cast<const float4*>(base + (size_t)r * IMG + c * 4);
        float vals[4] = {v.x, v.y, v.z, v.w};
#pragma unroll
        for (int k = 0; k < 4; ++k) {
            uint32_t key = __float_as_uint(vals[k]);
            if (key >= KEY_LO) {
                if (key < KEY_HI) atomicAdd(&hist[(key - KEY_LO) >> 13], 1u);
                else              atomicAdd(&hist[NBC], 1u);
            }
        }
    }
    __syncthreads();
    uint32_t* out = priv + (size_t)blockIdx.x * (NBC + 1);
    for (int i = t; i < NBC + 1; i += 256) out[i] = hist[i];
}

// ---------------- K2: combine + bin-locate (replicated) + candidate append ----
__global__ __launch_bounds__(256) void k_refine(const float* __restrict__ x,
                                                const uint32_t* __restrict__ priv,
                                                uint32_t* __restrict__ list,
                                                uint32_t* __restrict__ count,
                                                uint32_t* __restrict__ meta_r,
                                                uint32_t* __restrict__ meta_b) {
    __shared__ uint32_t comb[NBC + 1];
    __shared__ uint32_t partials[256];   // 4 desc bins each
    __shared__ uint32_t partial2[16];    // 16 partials each
    __shared__ uint32_t sel_bin_s[2];
    const int p = blockIdx.x >> 3, s = blockIdx.x & 7;
    const int t = threadIdx.x;
    const int pr = p >> 3, pc = p & 7;
    const float* base = x + (size_t)(pr * PH + s * SROWS) * IMG + pc * PH;

    for (int i = t; i < NBC + 1; i += 256) {
        uint32_t sum = 0;
#pragma unroll
        for (int b = 0; b < NSLICE; ++b)
            sum += priv[(size_t)(p * NSLICE + b) * (NBC + 1) + i];
        comb[i] = sum;
    }
    __syncthreads();
    {
        uint32_t sum = 0;
#pragma unroll
        for (int k = 0; k < 4; ++k) sum += comb[NBC - 1 - (4 * t + k)];
        partials[t] = sum;
    }
    __syncthreads();
    if (t < 16) {
        uint32_t sum = 0;
#pragma unroll
        for (int k = 0; k < 16; ++k) sum += partials[16 * t + k];
        partial2[t] = sum;
    }
    __syncthreads();
    if (t == 0) {
        uint32_t above = comb[NBC];
        uint32_t total = above;
        for (int u = 0; u < 16; ++u) total += partial2[u];
        int R[2];
        compute_ranks(is_frame(p), R[0], R[1]);
        for (int j = 0; j < 2; ++j) {
            int rank = R[j];
            if (rank < (int)above)  rank = (int)above;       // safety: v >= 1.0
            if (rank >= (int)total) rank = (int)total - 1;   // safety: v < 0.5
            uint32_t cum = above;
            int u = 15;
            for (int i = 0; i < 16; ++i) {
                if ((uint32_t)rank < cum + partial2[i]) { u = i; break; }
                cum += partial2[i];
            }
            int kk = 15;
            for (int i = 0; i < 16; ++i) {
                if ((uint32_t)rank < cum + partials[16 * u + i]) { kk = i; break; }
                cum += partials[16 * u + i];
            }
            int base_d = 4 * (16 * u + kk);
            uint32_t bin = NBC - 1 - base_d, r = 0;
            for (int b = 0; b < 4; ++b) {
                uint32_t h = comb[NBC - 1 - (base_d + b)];
                if ((uint32_t)rank < cum + h) { bin = NBC - 1 - (base_d + b); r = (uint32_t)rank - cum; break; }
                cum += h;
            }
            sel_bin_s[j] = bin;
            if (s == 0) { meta_b[p * 2 + j] = bin; meta_r[p * 2 + j] = r; }
        }
    }
    __syncthreads();
    const uint32_t b0 = sel_bin_s[0], b1 = sel_bin_s[1];
    constexpr int NF4 = SROWS * (PH / 4);
    for (int i = t; i < NF4; i += 256) {
        int r = i / 96, c = i - r * 96;
        float4 v = *reinterpret_cast<const float4*>(base + (size_t)r * IMG + c * 4);
        float vals[4] = {v.x, v.y, v.z, v.w};
#pragma unroll
        for (int k = 0; k < 4; ++k) {
            uint32_t key = __float_as_uint(vals[k]);
            if (key >= KEY_LO && key < KEY_HI) {
                uint32_t bin = (key - KEY_LO) >> 13;
                if (bin == b0) {
                    uint32_t idx = atomicAdd(&count[p * 2 + 0], 1u);
                    if (idx < CAP) list[(size_t)(p * 2 + 0) * CAP + idx] = key;
                }
                if (bin == b1) {
                    uint32_t idx = atomicAdd(&count[p * 2 + 1], 1u);
                    if (idx < CAP) list[(size_t)(p * 2 + 1) * CAP + idx] = key;
                }
            }
        }
    }
}

// ---------------- K3: exact r-th largest from candidate list (one wave/slot) ---
__global__ __launch_bounds__(64) void k_select(const uint32_t* __restrict__ list,
                                               const uint32_t* __restrict__ count,
                                               const uint32_t* __restrict__ meta_r,
                                               const uint32_t* __restrict__ meta_b,
                                               uint32_t* __restrict__ vbits) {
    __shared__ uint32_t keys[CAP];
    __shared__ uint32_t res;
    const int slot = blockIdx.x;
    const int t = threadIdx.x;
    uint32_t n = count[slot]; if (n > CAP) n = CAP;
    uint32_t r = meta_r[slot];
    if (t == 0) res = KEY_LO + (meta_b[slot] << 13);  // fallback (unreachable)
    for (uint32_t i = t; i < n; i += 64) keys[i] = list[(size_t)slot * CAP + i];
    __syncthreads();
    for (uint32_t ci = t; ci < n; ci += 64) {
        uint32_t c = keys[ci], gt = 0, ge = 0;
        for (uint32_t i = 0; i < n; ++i) {
            uint32_t k = keys[i];
            gt += (k > c);
            ge += (k >= c);
        }
        if (gt <= r && r < ge) res = c;  // duplicates write the same value
    }
    __syncthreads();
    if (t == 0) vbits[slot] = res;
}

// ---------------- pack: th chain (in-block) + binarize + bit-pack (verified) ---
__global__ __launch_bounds__(256) void k_pack(const float* __restrict__ x,
                                              const uint32_t* __restrict__ vbits,
                                              uint32_t* __restrict__ B) {
    __shared__ uint32_t vb[128];
    __shared__ float ths_s[NPATCH];
    int t = threadIdx.x;
    if (t < 128) vb[t] = vbits[t];
    __syncthreads();
    if (t == 0) {
        uint32_t b = 0x3F59999Au;  // bits(0.85f)
        for (int p = 0; p < NPATCH; ++p) {
            uint32_t bv1 = vb[2 * p], bv2 = vb[2 * p + 1];
            int d1 = (int)b - (int)bv1;
            if (d1 >= 0) b -= (uint32_t)(STEP_ULPS * (d1 / STEP_ULPS + 1));
            int d2 = (int)bv2 - (int)b;
            if (d2 > 0) b += (uint32_t)(STEP_ULPS * ((d2 + STEP_ULPS - 1) / STEP_ULPS));
            ths_s[p] = __uint_as_float(b);
        }
    }
    __syncthreads();
    int wi = blockIdx.x * 256 + t;
    if (wi >= NWORDS) return;
    int y  = wi / WPR;
    int wx = wi - y * WPR;
    float th = ths_s[(y / PH) * 8 + (wx * 32) / PH];
    const float* row = x + (size_t)y * IMG + wx * 32;
    uint32_t m = 0;
#pragma unroll
    for (int k = 0; k < 8; ++k) {
        float4 v = *reinterpret_cast<const float4*>(row + 4 * k);
        m |= (uint32_t)(v.x > th) << (4 * k + 0);
        m |= (uint32_t)(v.y > th) << (4 * k + 1);
        m |= (uint32_t)(v.z > th) << (4 * k + 2);
        m |= (uint32_t)(v.w > th) << (4 * k + 3);
    }
    B[wi] = m;
}

// ---------------- fused 5x5 close + f32 store, row-tile + halo in LDS ----------
__device__ __forceinline__ uint32_t hshift5_or(uint32_t c, uint32_t l, uint32_t r) {
    uint64_t xr = ((uint64_t)r << 32) | c;
    uint64_t xl = ((uint64_t)c << 32) | l;
    return c | (uint32_t)(xr >> 1) | (uint32_t)(xr >> 2)
             | (uint32_t)(xl >> 31) | (uint32_t)(xl >> 30);
}
__device__ __forceinline__ uint32_t hshift5_and(uint32_t c, uint32_t l, uint32_t r) {
    uint64_t xr = ((uint64_t)r << 32) | c;
    uint64_t xl = ((uint64_t)c << 32) | l;
    return c & (uint32_t)(xr >> 1) & (uint32_t)(xr >> 2)
             & (uint32_t)(xl >> 31) & (uint32_t)(xl >> 30);
}

__global__ __launch_bounds__(256) void k_close_store(const uint32_t* __restrict__ B,
                                                     float* __restrict__ out) {
    __shared__ uint32_t Bs[TR + 8][WPR];   // binary rows [y0-4, y0+TR+4)
    __shared__ uint32_t Ds[TR + 4][WPR];   // dilated rows [y0-2, y0+TR+2)
    const int y0 = blockIdx.x * TR;
    const int t = threadIdx.x;

    // load (zero-pad OOB rows: dilation pads with 0)
    for (int i = t; i < (TR + 8) * WPR; i += 256) {
        int r = i / WPR, c = i - r * WPR;
        int gy = y0 - 4 + r;
        Bs[r][c] = (gy >= 0 && gy < IMG) ? B[gy * WPR + c] : 0u;
    }
    __syncthreads();

    // dilate rows [y0-2, y0+TR+2): Ds[r] corresponds to Bs row r+2
    for (int i = t; i < (TR + 4) * WPR; i += 256) {
        int r = i / WPR, c = i - r * WPR;
        uint32_t acc = 0;
#pragma unroll
        for (int dy = -2; dy <= 2; ++dy) {
            int br = r + 2 + dy;
            uint32_t cc = Bs[br][c];
            uint32_t ll = (c > 0)       ? Bs[br][c - 1] : 0u;
            uint32_t rr = (c < WPR - 1) ? Bs[br][c + 1] : 0u;
            acc |= hshift5_or(cc, ll, rr);
        }
        Ds[r][c] = acc;
    }
    __syncthreads();

    // erode rows [y0, y0+TR) (OOB rows contribute 1s -> skip) + f32 store
    for (int i = t; i < TR * WPR; i += 256) {
        int r = i / WPR, c = i - r * WPR;
        int gy = y0 + r;
        uint32_t acc = 0xFFFFFFFFu;
#pragma unroll
        for (int dy = -2; dy <= 2; ++dy) {
            int yy = gy + dy;
            if (yy < 0 || yy >= IMG) continue;
            int dr = r + 2 + dy;   // Ds row index for global row yy
            uint32_t cc = Ds[dr][c];
            uint32_t ll = (c > 0)       ? Ds[dr][c - 1] : 0xFFFFFFFFu;
            uint32_t rr = (c < WPR - 1) ? Ds[dr][c + 1] : 0xFFFFFFFFu;
            acc &= hshift5_and(cc, ll, rr);
        }
        float* o = out + (size_t)gy * IMG + c * 32;
#pragma unroll
        for (int k = 0; k < 8; ++k) {
            float4 v;
            v.x = (acc & (1u << (4 * k + 0))) ? 1.0f : 0.0f;
            v.y = (acc & (1u << (4 * k + 1))) ? 1.0f : 0.0f;
            v.z = (acc & (1u << (4 * k + 2))) ? 1.0f : 0.0f;
            v.w = (acc & (1u << (4 * k + 3))) ? 1.0f : 0.0f;
            *reinterpret_cast<float4*>(o + 4 * k) = v;
        }
    }
}

extern "C" void kernel_launch(void* const* d_in, const int* in_sizes, int n_in,
                              void* d_out, int out_size, void* d_ws, size_t ws_size,
                              hipStream_t stream) {
    const float* x = (const float*)d_in[0];
    float* out = (float*)d_out;
    uint8_t* ws = (uint8_t*)d_ws;

    uint32_t* vbits  = (uint32_t*)(ws + OFF_VB);
    uint32_t* cnt    = (uint32_t*)(ws + OFF_CNT);
    uint32_t* meta_r = (uint32_t*)(ws + OFF_METAR);
    uint32_t* meta_b = (uint32_t*)(ws + OFF_METAB);
    uint32_t* priv   = (uint32_t*)(ws + OFF_PRIV);
    uint32_t* list   = (uint32_t*)(ws + OFF_LIST);
    uint32_t* Bb     = (uint32_t*)(ws + OFF_B);

    int gw = NWORDS / 256;  // 1152, exact

    k_coarse<<<NPATCH * NSLICE, 256, 0, stream>>>(x, priv, cnt);
    k_refine<<<NPATCH * NSLICE, 256, 0, stream>>>(x, priv, list, cnt, meta_r, meta_b);
    k_select<<<128, 64, 0, stream>>>(list, cnt, meta_r, meta_b, vbits);
    k_pack<<<gw, 256, 0, stream>>>(x, vbits, Bb);
    k_close_store<<<IMG / TR, 256, 0, stream>>>(Bb, out);
}